// Round 2
// baseline (82.823 us; speedup 1.0000x reference)
//
#include <hip/hip_runtime.h>

#define BSZ 9
#define NPB 2001            // outputs per (batch,bin) task: 9+45+165+495+1287
#define CHUNK 1024          // floats per wave (4 KB, aligned)
#define REG 56              // LDS floats per task region (55 used + pad)
#define MAGIC 137370269ULL  // floor(g/2001) = (g*MAGIC)>>38, exact for g < 2^27
#define MSHIFT 38

// LDS region slot map: 0..8 = singles v[i], 9..53 = pair products (lex), 54 = 1.0f
constexpr unsigned pslot(unsigned i, unsigned j) {   // i <= j
    return 9u + i * 9u - i * (i - 1u) / 2u + (j - i);
}

// Main table: each output j -> 3 slot indices (6 bits each), product of the 3.
struct Tab3 { unsigned pk[NPB]; };
constexpr Tab3 make_tab3() {
    Tab3 t{};
    int p = 0;
    constexpr unsigned ONE = 54;
    // order 1
    for (unsigned a = 0; a < 9; ++a)
        t.pk[p++] = a | (ONE << 6) | (ONE << 12);
    // order 2
    for (unsigned a = 0; a < 9; ++a)
        for (unsigned b = a; b < 9; ++b)
            t.pk[p++] = pslot(a, b) | (ONE << 6) | (ONE << 12);
    // order 3
    for (unsigned a = 0; a < 9; ++a)
        for (unsigned b = a; b < 9; ++b)
            for (unsigned c = b; c < 9; ++c)
                t.pk[p++] = pslot(a, b) | (c << 6) | (ONE << 12);
    // order 4
    for (unsigned a = 0; a < 9; ++a)
        for (unsigned b = a; b < 9; ++b)
            for (unsigned c = b; c < 9; ++c)
                for (unsigned d = c; d < 9; ++d)
                    t.pk[p++] = pslot(a, b) | (pslot(c, d) << 6) | (ONE << 12);
    // order 5
    for (unsigned a = 0; a < 9; ++a)
        for (unsigned b = a; b < 9; ++b)
            for (unsigned c = b; c < 9; ++c)
                for (unsigned d = c; d < 9; ++d)
                    for (unsigned e = d; e < 9; ++e)
                        t.pk[p++] = pslot(a, b) | (pslot(c, d) << 6) | (e << 12);
    return t;
}
__constant__ Tab3 g_tab = make_tab3();

// Pair index table: 45 entries, i | j<<8 in lex order
struct PTab { unsigned ij[45]; };
constexpr PTab make_ptab() {
    PTab t{};
    int p = 0;
    for (unsigned i = 0; i < 9; ++i)
        for (unsigned j = i; j < 9; ++j)
            t.ij[p++] = i | (j << 8);
    return t;
}
__constant__ PTab g_ptab = make_ptab();

__global__ __launch_bounds__(256) void poly_expand_kernel(
        const float* __restrict__ x, float* __restrict__ out,
        unsigned out_n, unsigned ntask) {
    __shared__ float L[4][2][REG];   // per-wave private: [wave][task_sel][slot]
    const int wave = threadIdx.x >> 6;
    const int lane = threadIdx.x & 63;
    const unsigned chunk = blockIdx.x * 4u + wave;
    const unsigned g0 = chunk * CHUNK;
    if (g0 >= out_n) return;   // no cross-wave sync anywhere: safe early exit

    const unsigned t0 = (unsigned)(((unsigned long long)g0 * MAGIC) >> MSHIFT);
    unsigned gLastEl = g0 + CHUNK - 1;
    if (gLastEl >= out_n) gLastEl = out_n - 1;
    const unsigned tLast = (unsigned)(((unsigned long long)gLastEl * MAGIC) >> MSHIFT);
    const bool twoTasks = (tLast > t0);
    const unsigned t1 = twoTasks ? (t0 + 1u) : t0;

    float (*Lw)[REG] = L[wave];

    // ---- per-wave staging (wave-internal ordering, no __syncthreads) ----
    if (lane < 9)                         Lw[0][lane]      = x[t0 * BSZ + lane];
    else if (lane == 9)                   Lw[0][54]        = 1.0f;
    else if (lane >= 16 && lane < 25)     Lw[1][lane - 16] = x[t1 * BSZ + (lane - 16)];
    else if (lane == 25)                  Lw[1][54]        = 1.0f;
    __builtin_amdgcn_wave_barrier();

    if (lane < 45) {
        const unsigned ij = g_ptab.ij[lane];
        Lw[0][9 + lane] = Lw[0][ij & 255u] * Lw[0][ij >> 8];
    }
    if (twoTasks && lane < 45) {
        const unsigned ij = g_ptab.ij[lane];
        Lw[1][9 + lane] = Lw[1][ij & 255u] * Lw[1][ij >> 8];
    }
    __builtin_amdgcn_wave_barrier();

    // ---- main loop: 4 aligned float4 stores per lane (1 KB/wave-instr) ----
    const float* Lb = &Lw[0][0];
    #pragma unroll
    for (int it = 0; it < 4; ++it) {
        const unsigned gb = g0 + (unsigned)(it * 256 + lane * 4);
        if (gb >= out_n) continue;
        float r[4];
        #pragma unroll
        for (int e = 0; e < 4; ++e) {
            const unsigned g = gb + (unsigned)e;
            const unsigned t = (unsigned)(((unsigned long long)g * MAGIC) >> MSHIFT);
            const unsigned j = g - t * (unsigned)NPB;
            const float* Ls = Lb + (t - t0) * REG;
            const unsigned pk = g_tab.pk[j];
            r[e] = Ls[pk & 63u] * Ls[(pk >> 6) & 63u] * Ls[(pk >> 12) & 63u];
        }
        if (gb + 4u <= out_n) {
            *reinterpret_cast<float4*>(out + gb) =
                make_float4(r[0], r[1], r[2], r[3]);
        } else {
            for (unsigned e = 0; e < 4 && gb + e < out_n; ++e)
                out[gb + e] = r[e];
        }
    }
}

extern "C" void kernel_launch(void* const* d_in, const int* in_sizes, int n_in,
                              void* d_out, int out_size, void* d_ws, size_t ws_size,
                              hipStream_t stream) {
    const float* x = (const float*)d_in[0];
    float* out = (float*)d_out;
    const unsigned ntask = (unsigned)(in_sizes[0] / BSZ);      // B * 35
    const unsigned out_n = (unsigned)out_size;                 // ntask * 2001
    const unsigned nchunk = (out_n + CHUNK - 1) / CHUNK;
    const unsigned blocks = (nchunk + 3) / 4;
    poly_expand_kernel<<<blocks, 256, 0, stream>>>(x, out, out_n, ntask);
}

// Round 3
// 64.971 us; speedup vs baseline: 1.2748x; 1.2748x over previous
//
#include <hip/hip_runtime.h>

#define BSZ 9
#define NPB 2001   // 9 + 45 + 165 + 495 + 1287
#define N2 45
#define N3 165
#define N4 495
#define N5 1287
#define O2 9       // LDS slot offset: pairs
#define O3 54      // triples
#define O4 219     // quads
#define O5 714     // (output offset of order-5; staged slots end here)
#define LSLOTS 720

constexpr unsigned pslot2(unsigned i, unsigned j) {   // slot of pair (i<=j)
    return O2 + i * 9u - i * (i - 1u) / 2u + (j - i);
}

// Incremental-staging tables. Slot layout in LDS == output layout for j<714:
// [0,9) singles, [9,54) pairs, [54,219) triples, [219,714) quads (all lex).
struct Tabs {
    unsigned short p2[N2];   // i | j<<8
    unsigned short p3[N3];   // pairslot | c<<8   (pairslot <= 53)
    unsigned short p4[N4];   // tripleslot | d<<8 (tripleslot <= 218)
    unsigned short p5[N5];   // quadslot | e<<10  (quadslot <= 713)
};
constexpr Tabs make_tabs() {
    Tabs t{};
    { int p = 0;
      for (unsigned i = 0; i < 9; ++i)
          for (unsigned j = i; j < 9; ++j)
              t.p2[p++] = (unsigned short)(i | (j << 8)); }
    { int p = 0;
      for (unsigned a = 0; a < 9; ++a)
          for (unsigned b = a; b < 9; ++b) {
              const unsigned ps = pslot2(a, b);
              for (unsigned c = b; c < 9; ++c)
                  t.p3[p++] = (unsigned short)(ps | (c << 8));
          } }
    { int p = 0; unsigned ts = O3;
      for (unsigned a = 0; a < 9; ++a)
          for (unsigned b = a; b < 9; ++b)
              for (unsigned c = b; c < 9; ++c) {
                  for (unsigned d = c; d < 9; ++d)
                      t.p4[p++] = (unsigned short)(ts | (d << 8));
                  ++ts;
              } }
    { int p = 0; unsigned qs = O4;
      for (unsigned a = 0; a < 9; ++a)
          for (unsigned b = a; b < 9; ++b)
              for (unsigned c = b; c < 9; ++c)
                  for (unsigned d = c; d < 9; ++d) {
                      for (unsigned e = d; e < 9; ++e)
                          t.p5[p++] = (unsigned short)(qs | (e << 10));
                      ++qs;
                  } }
    return t;
}
__constant__ Tabs g_tabs = make_tabs();

// One wave64 per (batch,bin) task; 4 waves per block.
__global__ __launch_bounds__(256) void poly_expand_kernel(
        const float* __restrict__ x, float* __restrict__ out, int ntask) {
    __shared__ float L[4][LSLOTS];
    const int wave = threadIdx.x >> 6;
    const int lane = threadIdx.x & 63;
    const int task = blockIdx.x * 4 + wave;
    const bool valid = task < ntask;
    float* Lw = L[wave];

    // Phase 0: singles
    if (valid && lane < 9) Lw[lane] = x[(size_t)task * BSZ + lane];
    __syncthreads();

    // Phase 1: pairs = single * single
    if (valid && lane < N2) {
        const unsigned pk = g_tabs.p2[lane];
        Lw[O2 + lane] = Lw[pk & 255u] * Lw[pk >> 8];
    }
    __syncthreads();

    // Phase 2: triples = pair * single (reads phase<=1 only; no intra-phase dep)
    if (valid) {
        #pragma unroll
        for (int k = 0; k < 3; ++k) {
            const int s = lane + 64 * k;
            if (s < N3) {
                const unsigned pk = g_tabs.p3[s];
                Lw[O3 + s] = Lw[pk & 255u] * Lw[pk >> 8];
            }
        }
    }
    __syncthreads();

    // Phase 3: quads = triple * single
    if (valid) {
        #pragma unroll
        for (int k = 0; k < 8; ++k) {
            const int s = lane + 64 * k;
            if (s < N4) {
                const unsigned pk = g_tabs.p4[s];
                Lw[O4 + s] = Lw[pk & 255u] * Lw[pk >> 8];
            }
        }
    }
    __syncthreads();

    if (!valid) return;
    const unsigned base = (unsigned)task * NPB;

    // Outputs, orders 1-4: straight LDS -> global copy (1 read, 0 mul)
    #pragma unroll
    for (int k = 0; k < 12; ++k) {
        const int j = lane + 64 * k;
        if (j < O5) out[base + j] = Lw[j];
    }

    // Outputs, order 5: quad * single (2 reads, 1 mul; 2nd read is 9-slot broadcast)
    #pragma unroll 4
    for (int k = 0; k < 21; ++k) {
        const int s = lane + 64 * k;
        if (s < N5) {
            const unsigned pk = g_tabs.p5[s];
            out[base + O5 + s] = Lw[pk & 1023u] * Lw[pk >> 10];
        }
    }
}

extern "C" void kernel_launch(void* const* d_in, const int* in_sizes, int n_in,
                              void* d_out, int out_size, void* d_ws, size_t ws_size,
                              hipStream_t stream) {
    const float* x = (const float*)d_in[0];
    float* out = (float*)d_out;
    const int ntask = in_sizes[0] / BSZ;            // B * 35
    const int blocks = (ntask + 3) / 4;
    poly_expand_kernel<<<blocks, 256, 0, stream>>>(x, out, ntask);
}

// Round 4
// 63.290 us; speedup vs baseline: 1.3086x; 1.0266x over previous
//
#include <hip/hip_runtime.h>

#define BSZ 9
#define NPB 2001   // 9 + 45 + 165 + 495 + 1287
#define N2 45
#define N3 165
#define N4 495
#define N5 1287
#define O2 9       // slot/output offset: pairs
#define O3 54      // triples
#define O4 219     // quads
#define O5 714     // order-5 output offset; staged LDS slots end here
#define LSLOTS 714

// Wave-internal LDS fence: compiler memory barrier + drain DS queue.
// Each wave uses a PRIVATE LDS region, so no cross-wave sync is needed.
#define WAVE_SYNC() asm volatile("s_waitcnt lgkmcnt(0)" ::: "memory")

constexpr unsigned pslot2(unsigned i, unsigned j) {   // slot of pair (i<=j)
    return O2 + i * 9u - i * (i - 1u) / 2u + (j - i);
}

// Incremental-staging tables. Slot layout in LDS == output layout for j<714:
// [0,9) singles, [9,54) pairs, [54,219) triples, [219,714) quads (all lex).
struct Tabs {
    unsigned short p2[N2];   // i | j<<8
    unsigned short p3[N3];   // pairslot | c<<8   (pairslot <= 53)
    unsigned short p4[N4];   // tripleslot | d<<8 (tripleslot <= 218)
    unsigned short p5[N5];   // quadslot | e<<10  (quadslot <= 713)
};
constexpr Tabs make_tabs() {
    Tabs t{};
    { int p = 0;
      for (unsigned i = 0; i < 9; ++i)
          for (unsigned j = i; j < 9; ++j)
              t.p2[p++] = (unsigned short)(i | (j << 8)); }
    { int p = 0;
      for (unsigned a = 0; a < 9; ++a)
          for (unsigned b = a; b < 9; ++b) {
              const unsigned ps = pslot2(a, b);
              for (unsigned c = b; c < 9; ++c)
                  t.p3[p++] = (unsigned short)(ps | (c << 8));
          } }
    { int p = 0; unsigned ts = O3;
      for (unsigned a = 0; a < 9; ++a)
          for (unsigned b = a; b < 9; ++b)
              for (unsigned c = b; c < 9; ++c) {
                  for (unsigned d = c; d < 9; ++d)
                      t.p4[p++] = (unsigned short)(ts | (d << 8));
                  ++ts;
              } }
    { int p = 0; unsigned qs = O4;
      for (unsigned a = 0; a < 9; ++a)
          for (unsigned b = a; b < 9; ++b)
              for (unsigned c = b; c < 9; ++c)
                  for (unsigned d = c; d < 9; ++d) {
                      for (unsigned e = d; e < 9; ++e)
                          t.p5[p++] = (unsigned short)(qs | (e << 10));
                      ++qs;
                  } }
    return t;
}
__constant__ Tabs g_tabs = make_tabs();

// One wave64 per (batch,bin) task; 4 waves per block; NO block-level sync.
__global__ __launch_bounds__(256) void poly_expand_kernel(
        const float* __restrict__ x, float* __restrict__ out, int ntask) {
    __shared__ float L[4][LSLOTS];
    const int wave = threadIdx.x >> 6;
    const int lane = threadIdx.x & 63;
    const int task = blockIdx.x * 4 + wave;
    if (task >= ntask) return;           // waves are independent: safe
    float* Lw = L[wave];
    const unsigned base = (unsigned)task * NPB;

    // Phase 0: singles -> LDS and straight to output
    if (lane < 9) {
        const float v = x[(size_t)task * BSZ + lane];
        Lw[lane] = v;
        out[base + lane] = v;
    }
    WAVE_SYNC();

    // Phase 1: pairs = single * single -> LDS + output (store from register)
    if (lane < N2) {
        const unsigned pk = g_tabs.p2[lane];
        const float v = Lw[pk & 255u] * Lw[pk >> 8];
        Lw[O2 + lane] = v;
        out[base + O2 + lane] = v;
    }
    WAVE_SYNC();

    // Phase 2: triples = pair * single
    #pragma unroll
    for (int k = 0; k < 3; ++k) {
        const int s = lane + 64 * k;
        if (s < N3) {
            const unsigned pk = g_tabs.p3[s];
            const float v = Lw[pk & 255u] * Lw[pk >> 8];
            Lw[O3 + s] = v;
            out[base + O3 + s] = v;
        }
    }
    WAVE_SYNC();

    // Phase 3: quads = triple * single
    #pragma unroll
    for (int k = 0; k < 8; ++k) {
        const int s = lane + 64 * k;
        if (s < N4) {
            const unsigned pk = g_tabs.p4[s];
            const float v = Lw[pk & 255u] * Lw[pk >> 8];
            Lw[O4 + s] = v;
            out[base + O4 + s] = v;
        }
    }
    WAVE_SYNC();

    // Phase 4: order-5 = quad * single (store only)
    #pragma unroll 4
    for (int k = 0; k < 21; ++k) {
        const int s = lane + 64 * k;
        if (s < N5) {
            const unsigned pk = g_tabs.p5[s];
            out[base + O5 + s] = Lw[pk & 1023u] * Lw[pk >> 10];
        }
    }
}

extern "C" void kernel_launch(void* const* d_in, const int* in_sizes, int n_in,
                              void* d_out, int out_size, void* d_ws, size_t ws_size,
                              hipStream_t stream) {
    const float* x = (const float*)d_in[0];
    float* out = (float*)d_out;
    const int ntask = in_sizes[0] / BSZ;            // B * 35
    const int blocks = (ntask + 3) / 4;
    poly_expand_kernel<<<blocks, 256, 0, stream>>>(x, out, ntask);
}

// Round 5
// 61.114 us; speedup vs baseline: 1.3552x; 1.0356x over previous
//
#include <hip/hip_runtime.h>

#define BSZ 9
#define NPB 2001   // 9 + 45 + 165 + 495 + 1287
#define N2 45
#define N3 165
#define N4 495
#define O2 9       // slot/output offset: pairs
#define O3 54      // triples
#define O4 219     // quads
#define ONE_SLOT 714
#define LSZ 740    // swizzled max index: sw(714)=736

// Wave-internal LDS fence (each wave's LDS region is private).
#define WAVE_SYNC() asm volatile("s_waitcnt lgkmcnt(0)" ::: "memory")

// LDS anti-bank-conflict swizzle: breaks stride-4 (8-way) down to 2-way (free).
__device__ __forceinline__ unsigned sw(unsigned s) { return s + (s >> 5); }
constexpr unsigned csw(unsigned s) { return s + (s >> 5); }

constexpr unsigned pslot2(unsigned i, unsigned j) {   // slot of pair (i<=j)
    return O2 + i * 9u - i * (i - 1u) / 2u + (j - i);
}

// Staging tables: lo8 = source slot (<256), hi8 = single index.
struct Tabs {
    unsigned short p2[N2];
    unsigned short p3[N3];
    unsigned short p4[N4];
};
constexpr Tabs make_tabs() {
    Tabs t{};
    { int p = 0;
      for (unsigned i = 0; i < 9; ++i)
          for (unsigned j = i; j < 9; ++j)
              t.p2[p++] = (unsigned short)(i | (j << 8)); }
    { int p = 0;
      for (unsigned a = 0; a < 9; ++a)
          for (unsigned b = a; b < 9; ++b) {
              const unsigned ps = pslot2(a, b);
              for (unsigned c = b; c < 9; ++c)
                  t.p3[p++] = (unsigned short)(ps | (c << 8));
          } }
    { int p = 0; unsigned ts = O3;
      for (unsigned a = 0; a < 9; ++a)
          for (unsigned b = a; b < 9; ++b)
              for (unsigned c = b; c < 9; ++c) {
                  for (unsigned d = c; d < 9; ++d)
                      t.p4[p++] = (unsigned short)(ts | (d << 8));
                  ++ts;
              } }
    return t;
}
__constant__ Tabs g_tabs = make_tabs();

// Unified output table: out[j] = Lw[lo16] * Lw[hi16]; slot 714 holds 1.0f.
struct Full { unsigned t[NPB]; };
constexpr Full make_full() {
    Full f{};
    for (unsigned j = 0; j < ONE_SLOT; ++j)
        f.t[j] = j | (ONE_SLOT << 16);
    { int p = ONE_SLOT; unsigned qs = O4;
      for (unsigned a = 0; a < 9; ++a)
          for (unsigned b = a; b < 9; ++b)
              for (unsigned c = b; c < 9; ++c)
                  for (unsigned d = c; d < 9; ++d) {
                      for (unsigned e = d; e < 9; ++e)
                          f.t[p++] = qs | (e << 16);
                      ++qs;
                  } }
    return f;
}
__constant__ Full g_full = make_full();

// One wave64 per (batch,bin) task; 4 waves/block; no cross-wave sync.
__global__ __launch_bounds__(256) void poly_expand_kernel(
        const float* __restrict__ x, float* __restrict__ out, int ntask) {
    __shared__ float L[4][LSZ];
    const int wave = threadIdx.x >> 6;
    const int lane = threadIdx.x & 63;
    const int task = blockIdx.x * 4 + wave;
    if (task >= ntask) return;
    float* Lw = L[wave];

    // ---- staging: incremental products into swizzled LDS slots ----
    if (lane < 9)        Lw[sw((unsigned)lane)] = x[(size_t)task * BSZ + lane];
    else if (lane == 9)  Lw[csw(ONE_SLOT)] = 1.0f;
    WAVE_SYNC();

    if (lane < N2) {
        const unsigned pk = g_tabs.p2[lane];
        Lw[sw(O2 + (unsigned)lane)] = Lw[sw(pk & 255u)] * Lw[sw(pk >> 8)];
    }
    WAVE_SYNC();

    #pragma unroll
    for (int k = 0; k < 3; ++k) {
        const int s = lane + 64 * k;
        if (s < N3) {
            const unsigned pk = g_tabs.p3[s];
            Lw[sw(O3 + (unsigned)s)] = Lw[sw(pk & 255u)] * Lw[sw(pk >> 8)];
        }
    }
    WAVE_SYNC();

    #pragma unroll
    for (int k = 0; k < 8; ++k) {
        const int s = lane + 64 * k;
        if (s < N4) {
            const unsigned pk = g_tabs.p4[s];
            Lw[sw(O4 + (unsigned)s)] = Lw[sw(pk & 255u)] * Lw[sw(pk >> 8)];
        }
    }
    WAVE_SYNC();

    // ---- aligned copy-out ----
    const unsigned rb = (unsigned)task * NPB;
    const unsigned h = (unsigned)((4 - (task & 3)) & 3);   // head to 16B boundary

    if (lane < (int)h) out[rb + lane] = Lw[sw((unsigned)lane)];  // singles, exact

    const unsigned n4 = (NPB - h) >> 2;   // 499 or 500 float4s
    #pragma unroll 2
    for (int k = 0; k < 8; ++k) {
        const unsigned i = (unsigned)lane + 64u * k;
        if (i < n4) {
            const unsigned j0 = h + 4u * i;
            float r[4];
            #pragma unroll
            for (int e = 0; e < 4; ++e) {
                const unsigned pk = g_full.t[j0 + e];
                r[e] = Lw[sw(pk & 0xFFFFu)] * Lw[sw(pk >> 16)];
            }
            *reinterpret_cast<float4*>(out + rb + j0) =
                make_float4(r[0], r[1], r[2], r[3]);
        }
    }

    const unsigned jt = h + 4u * n4;
    if (lane < (int)(NPB - jt)) {         // tail: 0..3 elements
        const unsigned j = jt + (unsigned)lane;
        const unsigned pk = g_full.t[j];
        out[rb + j] = Lw[sw(pk & 0xFFFFu)] * Lw[sw(pk >> 16)];
    }
}

extern "C" void kernel_launch(void* const* d_in, const int* in_sizes, int n_in,
                              void* d_out, int out_size, void* d_ws, size_t ws_size,
                              hipStream_t stream) {
    const float* x = (const float*)d_in[0];
    float* out = (float*)d_out;
    const int ntask = in_sizes[0] / BSZ;            // B * 35
    const int blocks = (ntask + 3) / 4;
    poly_expand_kernel<<<blocks, 256, 0, stream>>>(x, out, ntask);
}

// Round 6
// 52.033 us; speedup vs baseline: 1.5917x; 1.1745x over previous
//
#include <hip/hip_runtime.h>

#define BSZ 9
#define NPB 2001   // 9 + 45 + 165 + 495 + 1287
#define N2 45
#define N3 165
#define N4 495
#define O2 9
#define O3 54
#define O4 219
#define ONE_SLOT 714
#define LSZ 720
#define NBLOCKS 2048
#define STRIDE_T (NBLOCKS * 4)   // 8192; %4==0 keeps alignment class fixed

// Wave-internal LDS fence (each wave's LDS region is private).
#define WAVE_SYNC() asm volatile("s_waitcnt lgkmcnt(0)" ::: "memory")

constexpr unsigned pslot2(unsigned i, unsigned j) {   // slot of pair (i<=j)
    return O2 + i * 9u - i * (i - 1u) / 2u + (j - i);
}

// Staging tables: lo8 = source slot (<256), hi8 = single index.
struct Tabs { unsigned short p2[N2]; unsigned short p3[N3]; unsigned short p4[N4]; };
constexpr Tabs make_tabs() {
    Tabs t{};
    { int p = 0;
      for (unsigned i = 0; i < 9; ++i)
          for (unsigned j = i; j < 9; ++j)
              t.p2[p++] = (unsigned short)(i | (j << 8)); }
    { int p = 0;
      for (unsigned a = 0; a < 9; ++a)
          for (unsigned b = a; b < 9; ++b) {
              const unsigned ps = pslot2(a, b);
              for (unsigned c = b; c < 9; ++c)
                  t.p3[p++] = (unsigned short)(ps | (c << 8));
          } }
    { int p = 0; unsigned ts = O3;
      for (unsigned a = 0; a < 9; ++a)
          for (unsigned b = a; b < 9; ++b)
              for (unsigned c = b; c < 9; ++c) {
                  for (unsigned d = c; d < 9; ++d)
                      t.p4[p++] = (unsigned short)(ts | (d << 8));
                  ++ts;
              } }
    return t;
}
__constant__ Tabs g_tabs = make_tabs();

// Unified output table: out[j] = L[lo16 byte off] * L[hi16 byte off] (word o added
// via the shifted base pointer). Slot ONE_SLOT holds 1.0f.
struct Full { unsigned t[NPB]; };
constexpr Full make_full() {
    Full f{};
    for (unsigned j = 0; j < ONE_SLOT; ++j)
        f.t[j] = (4u * j) | ((4u * ONE_SLOT) << 16);
    { int p = ONE_SLOT; unsigned qs = O4;
      for (unsigned a = 0; a < 9; ++a)
          for (unsigned b = a; b < 9; ++b)
              for (unsigned c = b; c < 9; ++c)
                  for (unsigned d = c; d < 9; ++d) {
                      for (unsigned e = d; e < 9; ++e)
                          f.t[p++] = (4u * qs) | ((4u * e) << 16);
                      ++qs;
                  } }
    return f;
}
__constant__ Full g_full = make_full();

// Persistent: each wave owns tasks {w0, w0+8192, ...}; alignment class fixed.
__global__ __launch_bounds__(256) void poly_expand_kernel(
        const float* __restrict__ x, float* __restrict__ out, int ntask) {
    __shared__ float L[4][LSZ];
    const int wave = threadIdx.x >> 6;
    const int lane = threadIdx.x & 63;
    const int w0 = blockIdx.x * 4 + wave;
    if (w0 >= ntask) return;               // waves independent: safe
    float* const Lw = L[wave];

    // alignment geometry (loop-invariant: STRIDE_T % 4 == 0)
    const unsigned o     = (unsigned)w0 & 3u;           // rb & 3
    const unsigned a     = (4u - o) & 3u;               // head scalars
    const unsigned mA    = (ONE_SLOT - a) >> 2;         // full-A float4 groups
    const unsigned mB0   = (ONE_SLOT - a + 3u) >> 2;    // first full-B group
    const unsigned Mfull = (NPB - a) >> 2;              // == mB0 + 321
    float* const Ls = Lw + o;
    const char* const Lc = (const char*)Ls;
    const float4* const Af4 = (const float4*)(Lw + o + a);   // (o+a)%4==0

    // ---- hoisted per-lane loop invariants (tables -> registers) ----
    const unsigned t2 = (lane < N2) ? (unsigned)g_tabs.p2[lane] : 0u;
    unsigned t3[3], t4[8];
    #pragma unroll
    for (int k = 0; k < 3; ++k) { const int s = lane + 64 * k;
        t3[k] = (s < N3) ? (unsigned)g_tabs.p3[s] : 0u; }
    #pragma unroll
    for (int k = 0; k < 8; ++k) { const int s = lane + 64 * k;
        t4[k] = (s < N4) ? (unsigned)g_tabs.p4[s] : 0u; }

    const unsigned jb0 = a + 4u * mB0;     // first B-group output index
    unsigned bpk[6][4];
    #pragma unroll
    for (int k = 0; k < 6; ++k) {
        const unsigned idx = (unsigned)lane + 64u * k;
        #pragma unroll
        for (int e = 0; e < 4; ++e)
            bpk[k][e] = (idx < 321u) ? g_full.t[jb0 + 4u * idx + (unsigned)e] : 0u;
    }

    // misc elements: head [0,a) + straddle [a+4mA, a+4mB0) + tail [a+4Mfull, NPB)
    const unsigned z1s = a + 4u * mA, z1n = 4u * (mB0 - mA);
    const unsigned z2s = a + 4u * Mfull, z2n = (unsigned)NPB - z2s;
    int jm = -1;
    if ((unsigned)lane < a)                 jm = lane;
    else if ((unsigned)lane < a + z1n)      jm = (int)(z1s + ((unsigned)lane - a));
    else if ((unsigned)lane < a + z1n + z2n) jm = (int)(z2s + ((unsigned)lane - a - z1n));
    const unsigned mpk = (jm >= 0) ? g_full.t[jm] : 0u;

    // ---- persistent task loop ----
    for (int task = w0; task < ntask; task += STRIDE_T) {
        const unsigned rb = (unsigned)task * (unsigned)NPB;
        WAVE_SYNC();   // prior iteration's LDS reads retired before overwrite

        // stage singles
        if (lane < 9)       Ls[lane] = x[(size_t)task * BSZ + lane];
        else if (lane == 9) Ls[ONE_SLOT] = 1.0f;
        WAVE_SYNC();
        // pairs
        if (lane < N2) Ls[O2 + lane] = Ls[t2 & 255u] * Ls[t2 >> 8];
        WAVE_SYNC();
        // triples
        #pragma unroll
        for (int k = 0; k < 3; ++k) { const int s = lane + 64 * k;
            if (s < N3) Ls[O3 + s] = Ls[t3[k] & 255u] * Ls[t3[k] >> 8]; }
        WAVE_SYNC();
        // quads
        #pragma unroll
        for (int k = 0; k < 8; ++k) { const int s = lane + 64 * k;
            if (s < N4) Ls[O4 + s] = Ls[t4[k] & 255u] * Ls[t4[k] >> 8]; }
        WAVE_SYNC();

        float4* const po4 = (float4*)(out + rb + a);   // 16B-aligned

        // region A (orders<=4): straight LDS b128 -> global dwordx4
        #pragma unroll
        for (int k = 0; k < 3; ++k) {
            const unsigned m = (unsigned)lane + 64u * k;
            if (m < mA) po4[m] = Af4[m];
        }
        // region B (order 5): quad * single, hoisted byte-offset table
        #pragma unroll
        for (int k = 0; k < 6; ++k) {
            const unsigned idx = (unsigned)lane + 64u * k;
            if (idx < 321u) {
                float r[4];
                #pragma unroll
                for (int e = 0; e < 4; ++e) {
                    const unsigned pk = bpk[k][e];
                    r[e] = *(const float*)(Lc + (pk & 0xFFFFu)) *
                           *(const float*)(Lc + (pk >> 16));
                }
                po4[mB0 + idx] = make_float4(r[0], r[1], r[2], r[3]);
            }
        }
        // misc (<=9 lanes): head / straddle / tail scalars
        if (jm >= 0)
            out[rb + (unsigned)jm] = *(const float*)(Lc + (mpk & 0xFFFFu)) *
                                     *(const float*)(Lc + (mpk >> 16));
    }
}

extern "C" void kernel_launch(void* const* d_in, const int* in_sizes, int n_in,
                              void* d_out, int out_size, void* d_ws, size_t ws_size,
                              hipStream_t stream) {
    const float* x = (const float*)d_in[0];
    float* out = (float*)d_out;
    const int ntask = in_sizes[0] / BSZ;            // B * 35
    int blocks = (ntask + 3) / 4;
    if (blocks > NBLOCKS) blocks = NBLOCKS;
    poly_expand_kernel<<<blocks, 256, 0, stream>>>(x, out, ntask);
}